// Round 12
// baseline (204.681 us; speedup 1.0000x reference)
//
#include <hip/hip_runtime.h>

typedef __attribute__((ext_vector_type(16))) float f32x16;
typedef __attribute__((ext_vector_type(8))) short bf16x8;

__device__ __forceinline__ float bf2f(unsigned short u) {
  union { unsigned int i; float f; } x; x.i = ((unsigned int)u) << 16; return x.f;
}
__device__ __forceinline__ unsigned short f2bf(float f) {
  union { float f; unsigned int i; } x; x.f = f;
  unsigned int r = (x.i + 0x7FFFu + ((x.i >> 16) & 1u)) >> 16;
  return (unsigned short)r;
}

#define BARX __builtin_amdgcn_s_barrier()
#define VM0  asm volatile("s_waitcnt vmcnt(0)" ::: "memory")
#define GLD(gsrc, ldsoff)                                                        \
  __builtin_amdgcn_global_load_lds(                                              \
      (const __attribute__((address_space(1))) void*)(gsrc),                     \
      (__attribute__((address_space(3))) void*)&lds[ldsoff], 16, 0, 0)

// ---------------- convert f32 -> bf16 ----------------
__global__ __launch_bounds__(256) void cvt_f2b(const float* __restrict__ src,
                                               unsigned short* __restrict__ dst, long n4) {
  long i = (long)blockIdx.x * 256 + threadIdx.x;
  long stride = (long)gridDim.x * 256;
  for (; i < n4; i += stride) {
    float4 v = *(const float4*)&src[i * 4];
    ushort4 o;
    o.x = f2bf(v.x); o.y = f2bf(v.y); o.z = f2bf(v.z); o.w = f2bf(v.w);
    *(ushort4*)&dst[i * 4] = o;
  }
}

// ---------------- transpose f32[rows][cols] -> bf16[cols][rows] ----------------
__global__ __launch_bounds__(256) void transpose_f2b(const float* __restrict__ src,
                                                     unsigned short* __restrict__ dst,
                                                     int rows, int cols) {
  __shared__ float t[32][33];
  int bx = blockIdx.x * 32, by = blockIdx.y * 32;
  int tx = threadIdx.x, ty = threadIdx.y;
#pragma unroll
  for (int k = 0; k < 4; ++k)
    t[ty + 8 * k][tx] = src[(long)(by + ty + 8 * k) * cols + bx + tx];
  __syncthreads();
#pragma unroll
  for (int k = 0; k < 4; ++k)
    dst[(long)(bx + ty + 8 * k) * rows + by + tx] = f2bf(t[tx][ty + 8 * k]);
}

// ---------------- V slice of QKV [b][s][3072] -> VT[b][d][2064] (padded ld) ----------------
__global__ __launch_bounds__(512) void transpose_v(const unsigned short* __restrict__ src,
                                                   unsigned short* __restrict__ dst) {
  __shared__ unsigned short t[64][65];
  const long sb = (long)blockIdx.z * 2048 * 3072;
  const long db = (long)blockIdx.z * 1024 * 2064;
  const int d0 = blockIdx.x * 64;
  const int s0 = blockIdx.y * 64;
  const int tx = threadIdx.x, ty = threadIdx.y;  // block (64,8)
#pragma unroll
  for (int k = 0; k < 8; ++k)
    t[ty + 8 * k][tx] = src[sb + (long)(s0 + ty + 8 * k) * 3072 + d0 + tx];
  __syncthreads();
#pragma unroll
  for (int k = 0; k < 8; ++k)
    dst[db + (long)(d0 + ty + 8 * k) * 2064 + s0 + tx] = t[tx][ty + 8 * k];
}

// =========== 128x128 NT GEMM, 32x32x16 MFMA, single 32KiB buffer, chunked XCD swizzle ======
// C[m,n] = sum_k A[m,k]*B[n,k], bf16 in, fp32 acc. 4 waves (2M x 2N); per-wave C 64x64 as
// 2x2 of 32x32 tiles. BK=64 (4 K-steps of 16). Per tile: {8 GLD; vmcnt0; bar; 16 ds_read_b128
// + 16 MFMA_32x32x16 (~128 cyc vs ~160 for 32x 16x16x32); bar}. Latency hidden by co-resident
// blocks (m97/m114). __launch_bounds__(256,2): don't strangle the allocator (r9 lesson).
// LDS swizzle (verified r4-r10): 16B-group g of row r stored at g^(r&7); stage source
// pre-swizzled; fragment read quad (ks*2+lk)^(lane&7) -> per-thread-constant offsets.
// A-frag (32x32x16): row=lane&31, k = (lane>>5)*8 + j (natural extension of HW-verified
// 16x16x32 map; identical relabel on A and B cancels). C/D map [HW m74/m101]:
// col=lane&31, row=(reg&3)+8*(reg>>2)+4*(lane>>5).
// MODE 0: bf16(acc+bias_qkv[col]); MODE 1: bf16(exp(acc*scale));
// MODE 2: f32(acc/rowsum(A)) -- es[mi]=mfma(a,ones) shares the C/D map: division lane-local.
// r11 CRASH FIX: PV grid is (16 M, 8 N, 4 B) = 512; decode by=(nid>>4)&7, bz=nid>>7
// (r11's &3 / >>6 sent bz to 7 -> OOB reads -> page fault, and left cols 512..1023 unwritten).
template <int MODE>
__global__ __launch_bounds__(256, 2) void gemm32(const unsigned short* __restrict__ Ap_,
                                                 const unsigned short* __restrict__ Bp_,
                                                 void* __restrict__ Cv,
                                                 const float* __restrict__ q_,
                                                 const float* __restrict__ k_,
                                                 const float* __restrict__ v_,
                                                 int Kd, int lda, int ldb, int ldc, float scale,
                                                 long sA, long sB, long sC) {
  __shared__ unsigned short lds[16384];  // 32 KiB: A @0, B @8192 (elems)
  // chunked bijective XCD swizzle (grid%8==0): nid = (flat%8)*(n/8) + flat/8, x-fastest decode
  const int flat = blockIdx.x;
  int bx, by, bz;
  if (MODE == 0) {        // proj: 1536 = 8*192, grid (64 x-M, 24 y-N)
    const int nid = (flat & 7) * 192 + (flat >> 3);
    bx = nid & 63; by = nid >> 6; bz = 0;
  } else if (MODE == 1) { // scores: 1024 = 8*128, grid (16,16,4)
    const int nid = ((flat & 7) << 7) | (flat >> 3);
    bx = nid & 15; by = (nid >> 4) & 15; bz = nid >> 8;
  } else {                // PV: 512 = 8*64, grid (16,8,4)
    const int nid = ((flat & 7) << 6) | (flat >> 3);
    bx = nid & 15; by = (nid >> 4) & 7; bz = nid >> 7;
  }
  const int tid = threadIdx.x;
  const int m0 = bx * 128, n0 = by * 128;
  const int lane = tid & 63, wave = tid >> 6;
  const int wm = wave >> 1, wn = wave & 1;
  // staging map (global source pre-swizzled; LDS dest linear)
  const int rr = tid >> 3;
  const int cSrc = ((tid & 7) ^ (rr & 7)) << 3;
  // fragment-read map
  const int l31 = lane & 31, lk = lane >> 5, e = lane & 7;
  const int kof[4] = { ((0 + lk) ^ e) << 3, ((2 + lk) ^ e) << 3,
                       ((4 + lk) ^ e) << 3, ((6 + lk) ^ e) << 3 };
  const int ab = (wm * 64 + l31) * 64;
  const int bb = 8192 + (wn * 64 + l31) * 64;
  const int NT = Kd >> 6;

  const unsigned short* pA = Ap_ + (long)bz * sA + (long)(m0 + rr) * lda + cSrc;
  const unsigned short* pB = Bp_ + (long)bz * sB + (long)(n0 + rr) * ldb + cSrc;
  const long a32 = (long)32 * lda, b32 = (long)32 * ldb;

  f32x16 acc[2][2] = {};
  f32x16 es[2] = {};
  bf16x8 ones;
#pragma unroll
  for (int j = 0; j < 8; ++j) ones[j] = (short)0x3F80;  // bf16 1.0

  for (int t = 0; t < NT; ++t) {
    // ---- stage tile t into the single buffer
    GLD(pA, tid * 8);                  GLD(pA + a32, 2048 + tid * 8);
    GLD(pA + 2 * a32, 4096 + tid * 8); GLD(pA + 3 * a32, 6144 + tid * 8);
    GLD(pB, 8192 + tid * 8);           GLD(pB + b32, 10240 + tid * 8);
    GLD(pB + 2 * b32, 12288 + tid * 8); GLD(pB + 3 * b32, 14336 + tid * 8);
    VM0;
    BARX;
    // ---- B fragments (8) once; A per mi sub-phase
    bf16x8 bF[2][4], aF[4];
#pragma unroll
    for (int ni = 0; ni < 2; ++ni)
#pragma unroll
      for (int ks = 0; ks < 4; ++ks)
        bF[ni][ks] = *(const bf16x8*)&lds[bb + ni * 2048 + kof[ks]];
#pragma unroll
    for (int mi = 0; mi < 2; ++mi) {
#pragma unroll
      for (int ks = 0; ks < 4; ++ks)
        aF[ks] = *(const bf16x8*)&lds[ab + mi * 2048 + kof[ks]];
      __builtin_amdgcn_s_setprio(1);
#pragma unroll
      for (int ni = 0; ni < 2; ++ni)
#pragma unroll
        for (int ks = 0; ks < 4; ++ks)
          acc[mi][ni] = __builtin_amdgcn_mfma_f32_32x32x16_bf16(
              aF[ks], bF[ni][ks], acc[mi][ni], 0, 0, 0);
      if (MODE == 2) {
#pragma unroll
        for (int ks = 0; ks < 4; ++ks)
          es[mi] = __builtin_amdgcn_mfma_f32_32x32x16_bf16(aF[ks], ones, es[mi], 0, 0, 0);
      }
      __builtin_amdgcn_s_setprio(0);
    }
    BARX;  // all waves done reading -> next stage may overwrite
    pA += 64; pB += 64;
  }

  // ---- epilogue: C/D map col=lane&31, row=(reg&3)+8*(reg>>2)+4*(lane>>5)
  const int c0 = n0 + wn * 64 + l31;
  if (MODE == 2) {
    float* O = (float*)Cv + (long)bz * sC;
#pragma unroll
    for (int mi = 0; mi < 2; ++mi) {
      const int rbase = m0 + wm * 64 + mi * 32 + 4 * lk;
#pragma unroll
      for (int reg = 0; reg < 16; ++reg) {
        const int row = rbase + (reg & 3) + 8 * (reg >> 2);
        const float iv = 1.0f / es[mi][reg];
#pragma unroll
        for (int ni = 0; ni < 2; ++ni)
          O[(long)row * ldc + (c0 + ni * 32)] = acc[mi][ni][reg] * iv;
      }
    }
  } else {
    unsigned short* C = (unsigned short*)Cv + (long)bz * sC;
#pragma unroll
    for (int ni = 0; ni < 2; ++ni) {
      const int col = c0 + ni * 32;
      float bv = 0.0f;
      if (MODE == 0)
        bv = (col < 1024) ? q_[col] : ((col < 2048) ? k_[col - 1024] : v_[col - 2048]);
#pragma unroll
      for (int mi = 0; mi < 2; ++mi) {
        const int rbase = m0 + wm * 64 + mi * 32 + 4 * lk;
#pragma unroll
        for (int reg = 0; reg < 16; ++reg) {
          const int row = rbase + (reg & 3) + 8 * (reg >> 2);
          float val = acc[mi][ni][reg];
          val = (MODE == 0) ? (val + bv) : __expf(val * scale);
          C[(long)row * ldc + col] = f2bf(val);
        }
      }
    }
  }
}

extern "C" void kernel_launch(void* const* d_in, const int* in_sizes, int n_in,
                              void* d_out, int out_size, void* d_ws, size_t ws_size,
                              hipStream_t stream) {
  const float* x  = (const float*)d_in[0];
  const float* Wq = (const float*)d_in[1];
  const float* bq = (const float*)d_in[2];
  const float* Wk = (const float*)d_in[3];
  const float* bk = (const float*)d_in[4];
  const float* Wv = (const float*)d_in[5];
  const float* bv = (const float*)d_in[6];
  float* out = (float*)d_out;

  const int Bb = 4, S = 2048, D = 1024;
  const long MS = (long)Bb * S;  // 8192
  const int LDP = 2064;          // padded ld for E and VT

  // ---- workspace layout ----
  char* ws = (char*)d_ws;
  unsigned short* xb  = (unsigned short*)(ws);                 // 16 MiB (x bf16; reused by VT)
  unsigned short* Wt  = (unsigned short*)(ws + (16L << 20));   // 6 MiB [3072][1024]
  unsigned short* QKV = (unsigned short*)(ws + (22L << 20));   // 48 MiB [8192][3072]
  unsigned short* Sc  = (unsigned short*)(ws + (70L << 20));   // 32.25 MiB [B][2048][2064] (E)
  unsigned short* VT  = xb;  // [B][1024][2064] = 16.125 MiB; 0.125 spills into dead Wt region

  // 1) x -> bf16
  cvt_f2b<<<2048, 256, 0, stream>>>(x, xb, MS * D / 4);

  // 2) W -> bf16 transposed, concatenated [3072][1024]
  dim3 tb(32, 8);
  dim3 tg(D / 32, D / 32);
  transpose_f2b<<<tg, tb, 0, stream>>>(Wq, Wt, D, D);
  transpose_f2b<<<tg, tb, 0, stream>>>(Wk, Wt + 1024 * 1024, D, D);
  transpose_f2b<<<tg, tb, 0, stream>>>(Wv, Wt + 2 * 1024 * 1024, D, D);

  // 3) fused QKV projection: [8192][3072] = x @ [Wq|Wk|Wv] + bias  (1536 blocks, chunked XCD)
  gemm32<0><<<1536, 256, 0, stream>>>(xb, Wt, QKV, bq, bk, bv,
                                      D, D, D, 3072, 1.0f, 0, 0, 0);

  // 4) V -> VT per batch (padded ld)
  dim3 vtb(64, 8);
  dim3 vtg(D / 64, S / 64, Bb);
  transpose_v<<<vtg, vtb, 0, stream>>>(QKV + 2048, VT);

  // 5) E = exp(Q @ K^T / 32), bf16, padded ldc (no max-shift)  (1024 blocks, chunked XCD)
  gemm32<1><<<1024, 256, 0, stream>>>(QKV, QKV + 1024, Sc, nullptr, nullptr, nullptr,
                                      D, 3072, 3072, LDP, 1.0f / 32.0f,
                                      (long)S * 3072, (long)S * 3072, (long)S * LDP);

  // 6) out = (E @ V) / rowsum(E), fp32 — MFMA-fused denominator  (512 blocks, chunked XCD)
  gemm32<2><<<512, 256, 0, stream>>>(Sc, VT, out, nullptr, nullptr, nullptr,
                                     2048, LDP, LDP, D, 1.0f,
                                     (long)S * LDP, (long)D * LDP, (long)S * D);
}

// Round 13
// 194.898 us; speedup vs baseline: 1.0502x; 1.0502x over previous
//
#include <hip/hip_runtime.h>

typedef __attribute__((ext_vector_type(4))) float f32x4;
typedef __attribute__((ext_vector_type(8))) short bf16x8;

__device__ __forceinline__ float bf2f(unsigned short u) {
  union { unsigned int i; float f; } x; x.i = ((unsigned int)u) << 16; return x.f;
}
__device__ __forceinline__ unsigned short f2bf(float f) {
  union { float f; unsigned int i; } x; x.f = f;
  unsigned int r = (x.i + 0x7FFFu + ((x.i >> 16) & 1u)) >> 16;
  return (unsigned short)r;
}

#define BARX __builtin_amdgcn_s_barrier()
#define VM0  asm volatile("s_waitcnt vmcnt(0)" ::: "memory")
#define GLD(gsrc, ldsoff)                                                        \
  __builtin_amdgcn_global_load_lds(                                              \
      (const __attribute__((address_space(1))) void*)(gsrc),                     \
      (__attribute__((address_space(3))) void*)&lds[ldsoff], 16, 0, 0)

// ---------------- convert f32 -> bf16 ----------------
__global__ __launch_bounds__(256) void cvt_f2b(const float* __restrict__ src,
                                               unsigned short* __restrict__ dst, long n4) {
  long i = (long)blockIdx.x * 256 + threadIdx.x;
  long stride = (long)gridDim.x * 256;
  for (; i < n4; i += stride) {
    float4 v = *(const float4*)&src[i * 4];
    ushort4 o;
    o.x = f2bf(v.x); o.y = f2bf(v.y); o.z = f2bf(v.z); o.w = f2bf(v.w);
    *(ushort4*)&dst[i * 4] = o;
  }
}

// ---------------- transpose f32[rows][cols] -> bf16[cols][rows] ----------------
__global__ __launch_bounds__(256) void transpose_f2b(const float* __restrict__ src,
                                                     unsigned short* __restrict__ dst,
                                                     int rows, int cols) {
  __shared__ float t[32][33];
  int bx = blockIdx.x * 32, by = blockIdx.y * 32;
  int tx = threadIdx.x, ty = threadIdx.y;
#pragma unroll
  for (int k = 0; k < 4; ++k)
    t[ty + 8 * k][tx] = src[(long)(by + ty + 8 * k) * cols + bx + tx];
  __syncthreads();
#pragma unroll
  for (int k = 0; k < 4; ++k)
    dst[(long)(bx + ty + 8 * k) * rows + by + tx] = f2bf(t[tx][ty + 8 * k]);
}

// ---------------- V slice of QKV [b][s][3072] -> VT[b][d][2064] (padded ld) ----------------
__global__ __launch_bounds__(512) void transpose_v(const unsigned short* __restrict__ src,
                                                   unsigned short* __restrict__ dst) {
  __shared__ unsigned short t[64][65];
  const long sb = (long)blockIdx.z * 2048 * 3072;
  const long db = (long)blockIdx.z * 1024 * 2064;
  const int d0 = blockIdx.x * 64;
  const int s0 = blockIdx.y * 64;
  const int tx = threadIdx.x, ty = threadIdx.y;  // block (64,8)
#pragma unroll
  for (int k = 0; k < 8; ++k)
    t[ty + 8 * k][tx] = src[sb + (long)(s0 + ty + 8 * k) * 3072 + d0 + tx];
  __syncthreads();
#pragma unroll
  for (int k = 0; k < 8; ++k)
    dst[db + (long)(d0 + ty + 8 * k) * 2064 + s0 + tx] = t[tx][ty + 8 * k];
}

// ====== 128x256 NT GEMM, wave-tile 64x128, single 48KiB buffer (r10 schedule widened) ======
// C[m,n] = sum_k A[m,k]*B[n,k], bf16 in, fp32 acc. 4 waves (2M x 2N), per-wave C 64x128.
// BK=64. LDS 48 KiB = A[128][64] @0 + B[256][64] @8192 (elems). Per K-tile:
//   {12 global_load_lds; vmcnt(0); barrier; 24 ds_read_b128 + 64 MFMA; barrier}
// vs r10: 2x MFMA per tile at the same sync cost -> per-FLOP barrier/drain overhead halves;
// LDS reads/FLOP -25%. Registers ~200 unified -> 2 waves/SIMD (m69 quantum), 2 blocks/CU.
// Swizzle: byte-identical to r10 (16B-group g of row r at g^(r&7), source pre-swizzled,
// per-thread-constant read XOR; conflict-free, SQ_LDS_BANK_CONFLICT=0 verified r4-r10).
// 16x16x32 MFMA (r12's 32x32 fragment reads 4-way conflict: row stride 128B = all 32 banks,
// bank = f(quad only); lanes {l,l+8,l+16,l+24} share quad. Reverted).
// No XCD swizzle on proj/scores (r12: chunked swizzle tripled proj FETCH -> L3 thrash).
// MODE 0: bf16(acc+bias_qkv[col]); MODE 1: bf16(exp(acc*scale));
// MODE 2: f32(acc/rowsum(A)), rowsum via mfma(a,ones) lane-local (verified r8/r10).
template <int MODE>
__global__ __launch_bounds__(256, 2) void gemmw(const unsigned short* __restrict__ Ap_,
                                                const unsigned short* __restrict__ Bp_,
                                                void* __restrict__ Cv,
                                                const float* __restrict__ q_,
                                                const float* __restrict__ k_,
                                                const float* __restrict__ v_,
                                                int Kd, int lda, int ldb, int ldc, float scale,
                                                long sA, long sB, long sC) {
  __shared__ unsigned short lds[24576];  // 48 KiB: A @0 (8192 elems), B @8192 (16384 elems)
  int bx, by, bz;
  if (MODE == 2) {
    // T1 bijective XCD swizzle (as r10): 256 blocks = 8 XCDs x 32; grid (16,4,4) x-fastest
    const int flat = blockIdx.x;
    const int nid = ((flat & 7) << 5) | (flat >> 3);
    bx = nid & 15; by = (nid >> 4) & 3; bz = nid >> 6;
  } else {
    bx = blockIdx.x; by = blockIdx.y; bz = blockIdx.z;
  }
  const int tid = threadIdx.x;
  const int m0 = bx * 128, n0 = by * 256;
  const int lane = tid & 63, wave = tid >> 6;
  const int wm = wave >> 1, wn = wave & 1;
  // staging map (global source pre-swizzled; LDS dest linear)
  const int rr = tid >> 3;                       // 0..31
  const int cSrc = ((tid & 7) ^ (rr & 7)) << 3;  // swizzled source col (elems)
  // fragment-read map (per-thread-constant swizzle terms; row mod 16 == lc)
  const int lc = lane & 15, lr = lane >> 4;
  const int x0 = (lc & 4) << 3;
  const int x1 = 32 ^ x0;
  const int klo = (lr << 3) ^ ((lc & 3) << 3);
  const int aoff = (wm * 64 + lc) * 64 + klo;
  const int boff = 8192 + (wn * 128 + lc) * 64 + klo;
  const int NT = Kd >> 6;

  const unsigned short* pA = Ap_ + (long)bz * sA + (long)(m0 + rr) * lda + cSrc;
  const unsigned short* pB = Bp_ + (long)bz * sB + (long)(n0 + rr) * ldb + cSrc;
  const long a32 = (long)32 * lda, b32 = (long)32 * ldb;

  f32x4 acc[4][8] = {};
  f32x4 es[4] = {};
  bf16x8 ones;
#pragma unroll
  for (int j = 0; j < 8; ++j) ones[j] = (short)0x3F80;  // bf16 1.0

  for (int t = 0; t < NT; ++t) {
    // ---- stage tile t into the single buffer: A 4 rounds, B 8 rounds
    GLD(pA, tid * 8);                   GLD(pA + a32, 2048 + tid * 8);
    GLD(pA + 2 * a32, 4096 + tid * 8);  GLD(pA + 3 * a32, 6144 + tid * 8);
#pragma unroll
    for (int rB = 0; rB < 8; ++rB)
      GLD(pB + rB * b32, 8192 + rB * 2048 + tid * 8);
    VM0;
    BARX;
    // ---- A fragments (8 reads) held; B streamed per ni (16 reads)
    bf16x8 a[4][2];
#pragma unroll
    for (int mi = 0; mi < 4; ++mi) {
      a[mi][0] = *(const bf16x8*)&lds[aoff + mi * 1024 + x0];
      a[mi][1] = *(const bf16x8*)&lds[aoff + mi * 1024 + x1];
    }
#pragma unroll
    for (int ni = 0; ni < 8; ++ni) {
      bf16x8 b0 = *(const bf16x8*)&lds[boff + ni * 1024 + x0];
      bf16x8 b1 = *(const bf16x8*)&lds[boff + ni * 1024 + x1];
      __builtin_amdgcn_s_setprio(1);
#pragma unroll
      for (int mi = 0; mi < 4; ++mi) {
        acc[mi][ni] = __builtin_amdgcn_mfma_f32_16x16x32_bf16(a[mi][0], b0, acc[mi][ni], 0, 0, 0);
        acc[mi][ni] = __builtin_amdgcn_mfma_f32_16x16x32_bf16(a[mi][1], b1, acc[mi][ni], 0, 0, 0);
      }
      __builtin_amdgcn_s_setprio(0);
    }
    if (MODE == 2) {
      __builtin_amdgcn_s_setprio(1);
#pragma unroll
      for (int mi = 0; mi < 4; ++mi) {
        es[mi] = __builtin_amdgcn_mfma_f32_16x16x32_bf16(a[mi][0], ones, es[mi], 0, 0, 0);
        es[mi] = __builtin_amdgcn_mfma_f32_16x16x32_bf16(a[mi][1], ones, es[mi], 0, 0, 0);
      }
      __builtin_amdgcn_s_setprio(0);
    }
    BARX;  // all waves done reading -> next tile's stage may overwrite
    pA += 64; pB += 64;
  }

  // ---- epilogue: C/D map col=lane&15, row=4*(lane>>4)+r; acc[mi][ni] = (mi*16, ni*16)
  const int r0 = m0 + wm * 64 + lr * 4;
  const int c0 = n0 + wn * 128 + lc;
  if (MODE == 2) {
    float* O = (float*)Cv + (long)bz * sC;
#pragma unroll
    for (int mi = 0; mi < 4; ++mi)
#pragma unroll
      for (int r = 0; r < 4; ++r) {
        const float iv = 1.0f / es[mi][r];  // rowsum of row r0+mi*16+r, lane-local
#pragma unroll
        for (int ni = 0; ni < 8; ++ni)
          O[(long)(r0 + mi * 16 + r) * ldc + (c0 + ni * 16)] = acc[mi][ni][r] * iv;
      }
  } else {
    unsigned short* C = (unsigned short*)Cv + (long)bz * sC;
#pragma unroll
    for (int ni = 0; ni < 8; ++ni) {
      const int col = c0 + ni * 16;
      float bv = 0.0f;
      if (MODE == 0)
        bv = (col < 1024) ? q_[col] : ((col < 2048) ? k_[col - 1024] : v_[col - 2048]);
#pragma unroll
      for (int mi = 0; mi < 4; ++mi)
#pragma unroll
        for (int r = 0; r < 4; ++r) {
          float val = acc[mi][ni][r];
          val = (MODE == 0) ? (val + bv) : __expf(val * scale);
          C[(long)(r0 + mi * 16 + r) * ldc + col] = f2bf(val);
        }
    }
  }
}

extern "C" void kernel_launch(void* const* d_in, const int* in_sizes, int n_in,
                              void* d_out, int out_size, void* d_ws, size_t ws_size,
                              hipStream_t stream) {
  const float* x  = (const float*)d_in[0];
  const float* Wq = (const float*)d_in[1];
  const float* bq = (const float*)d_in[2];
  const float* Wk = (const float*)d_in[3];
  const float* bk = (const float*)d_in[4];
  const float* Wv = (const float*)d_in[5];
  const float* bv = (const float*)d_in[6];
  float* out = (float*)d_out;

  const int Bb = 4, S = 2048, D = 1024;
  const long MS = (long)Bb * S;  // 8192
  const int LDP = 2064;          // padded ld for E and VT

  // ---- workspace layout ----
  char* ws = (char*)d_ws;
  unsigned short* xb  = (unsigned short*)(ws);                 // 16 MiB (x bf16; reused by VT)
  unsigned short* Wt  = (unsigned short*)(ws + (16L << 20));   // 6 MiB [3072][1024]
  unsigned short* QKV = (unsigned short*)(ws + (22L << 20));   // 48 MiB [8192][3072]
  unsigned short* Sc  = (unsigned short*)(ws + (70L << 20));   // 32.25 MiB [B][2048][2064] (E)
  unsigned short* VT  = xb;  // [B][1024][2064] = 16.125 MiB; 0.125 spills into dead Wt region

  // 1) x -> bf16
  cvt_f2b<<<2048, 256, 0, stream>>>(x, xb, MS * D / 4);

  // 2) W -> bf16 transposed, concatenated [3072][1024]
  dim3 tb(32, 8);
  dim3 tg(D / 32, D / 32);
  transpose_f2b<<<tg, tb, 0, stream>>>(Wq, Wt, D, D);
  transpose_f2b<<<tg, tb, 0, stream>>>(Wk, Wt + 1024 * 1024, D, D);
  transpose_f2b<<<tg, tb, 0, stream>>>(Wv, Wt + 2 * 1024 * 1024, D, D);

  // 3) fused QKV projection: [8192][3072] = x @ [Wq|Wk|Wv] + bias  (768 blocks)
  dim3 pgrid(MS / 128, 3072 / 256, 1);
  gemmw<0><<<pgrid, 256, 0, stream>>>(xb, Wt, QKV, bq, bk, bv,
                                      D, D, D, 3072, 1.0f, 0, 0, 0);

  // 4) V -> VT per batch (padded ld)
  dim3 vtb(64, 8);
  dim3 vtg(D / 64, S / 64, Bb);
  transpose_v<<<vtg, vtb, 0, stream>>>(QKV + 2048, VT);

  // 5) E = exp(Q @ K^T / 32), bf16, padded ldc (no max-shift)  (512 blocks)
  dim3 sgrid(S / 128, S / 256, Bb);
  gemmw<1><<<sgrid, 256, 0, stream>>>(QKV, QKV + 1024, Sc, nullptr, nullptr, nullptr,
                                      D, 3072, 3072, LDP, 1.0f / 32.0f,
                                      (long)S * 3072, (long)S * 3072, (long)S * LDP);

  // 6) out = (E @ V) / rowsum(E), fp32 — MFMA-fused denominator, XCD swizzle  (256 blocks)
  gemmw<2><<<256, 256, 0, stream>>>(Sc, VT, out, nullptr, nullptr, nullptr,
                                    2048, LDP, LDP, D, 1.0f,
                                    (long)S * LDP, (long)D * LDP, (long)S * D);
}

// Round 14
// 171.862 us; speedup vs baseline: 1.1910x; 1.1340x over previous
//
#include <hip/hip_runtime.h>

typedef __attribute__((ext_vector_type(4))) float f32x4;
typedef __attribute__((ext_vector_type(8))) short bf16x8;

__device__ __forceinline__ float bf2f(unsigned short u) {
  union { unsigned int i; float f; } x; x.i = ((unsigned int)u) << 16; return x.f;
}
__device__ __forceinline__ unsigned short f2bf(float f) {
  union { float f; unsigned int i; } x; x.f = f;
  unsigned int r = (x.i + 0x7FFFu + ((x.i >> 16) & 1u)) >> 16;
  return (unsigned short)r;
}

#define BARX __builtin_amdgcn_s_barrier()
#define VM0  asm volatile("s_waitcnt vmcnt(0)" ::: "memory")
#define GLD(gsrc, ldsoff)                                                        \
  __builtin_amdgcn_global_load_lds(                                              \
      (const __attribute__((address_space(1))) void*)(gsrc),                     \
      (__attribute__((address_space(3))) void*)&lds[ldsoff], 16, 0, 0)

// ---------------- convert f32 -> bf16 ----------------
__global__ __launch_bounds__(256) void cvt_f2b(const float* __restrict__ src,
                                               unsigned short* __restrict__ dst, long n4) {
  long i = (long)blockIdx.x * 256 + threadIdx.x;
  long stride = (long)gridDim.x * 256;
  for (; i < n4; i += stride) {
    float4 v = *(const float4*)&src[i * 4];
    ushort4 o;
    o.x = f2bf(v.x); o.y = f2bf(v.y); o.z = f2bf(v.z); o.w = f2bf(v.w);
    *(ushort4*)&dst[i * 4] = o;
  }
}

// ---------------- transpose f32[rows][cols] -> bf16[cols][rows] ----------------
__global__ __launch_bounds__(256) void transpose_f2b(const float* __restrict__ src,
                                                     unsigned short* __restrict__ dst,
                                                     int rows, int cols) {
  __shared__ float t[32][33];
  int bx = blockIdx.x * 32, by = blockIdx.y * 32;
  int tx = threadIdx.x, ty = threadIdx.y;
#pragma unroll
  for (int k = 0; k < 4; ++k)
    t[ty + 8 * k][tx] = src[(long)(by + ty + 8 * k) * cols + bx + tx];
  __syncthreads();
#pragma unroll
  for (int k = 0; k < 4; ++k)
    dst[(long)(bx + ty + 8 * k) * rows + by + tx] = f2bf(t[tx][ty + 8 * k]);
}

// =================== 128x128 NT GEMM, r10 structure (verified 173.98 total) ===============
// Single 32 KiB LDS buffer, 4 waves (2Mx2N), per-wave C 64x64, BK=64, 16x16x32 MFMA.
// Per K-tile: {8 global_load_lds; vmcnt(0); barrier; 16 ds_read_b128 + 32 MFMA; barrier}.
// Latency hidden by ~2-3 co-resident blocks/CU (m97/m114). (256,2) bound: no spill (r9 lesson).
// Swizzle (verified r4-r10, conflicts=0): 16B-group g of row r stored at g^(r&7).
// MODE 0 (proj): cols<2048 -> bf16(acc+bias) row-major into QK (ld 2080);
//                cols>=2048 (wave-uniform) -> V part written TRANSPOSED into VT[d][s] (ld
//                2064), bias pre-added -- fuses the old transpose_v pass into the epilogue.
// MODE 1 (scores): bf16(exp(acc*scale)).
// MODE 2 (PV): f32(acc/rowsum(A)); rowsum via mfma(a,ones), lane-local (verified r8/r10).
template <int MODE>
__global__ __launch_bounds__(256, 2) void gemmo(const unsigned short* __restrict__ Ap_,
                                                const unsigned short* __restrict__ Bp_,
                                                void* __restrict__ Cv,
                                                void* __restrict__ vtv,
                                                const float* __restrict__ q_,
                                                const float* __restrict__ k_,
                                                const float* __restrict__ v_,
                                                int Kd, int lda, int ldb, int ldc, float scale,
                                                long sA, long sB, long sC) {
  __shared__ unsigned short lds[16384];  // 32 KiB: A @0, B @8192 (elems)
  int bx, by, bz;
  if (MODE == 2) {
    // T1 bijective XCD swizzle: 512 blocks = 8 XCDs x 64; grid (16,8,4) x-fastest
    const int flat = blockIdx.x;
    const int nid = ((flat & 7) << 6) | (flat >> 3);
    bx = nid & 15; by = (nid >> 4) & 7; bz = nid >> 7;
  } else {
    bx = blockIdx.x; by = blockIdx.y; bz = blockIdx.z;
  }
  const int tid = threadIdx.x;
  const int m0 = bx * 128, n0 = by * 128;
  const int lane = tid & 63, wave = tid >> 6;
  const int wm = wave >> 1, wn = wave & 1;
  // staging map (global source pre-swizzled; LDS dest linear)
  const int rr = tid >> 3;                       // 0..31
  const int cSrc = ((tid & 7) ^ (rr & 7)) << 3;  // swizzled source col (elems)
  // fragment-read map (per-thread-constant swizzle terms)
  const int lc = lane & 15, lr = lane >> 4;
  const int x0 = (lc & 4) << 3;
  const int x1 = 32 ^ x0;
  const int klo = (lr << 3) ^ ((lc & 3) << 3);
  const int aoff = (wm * 64 + lc) * 64 + klo;
  const int boff = 8192 + (wn * 64 + lc) * 64 + klo;
  const int NT = Kd >> 6;

  const unsigned short* pA = Ap_ + (long)bz * sA + (long)(m0 + rr) * lda + cSrc;
  const unsigned short* pB = Bp_ + (long)bz * sB + (long)(n0 + rr) * ldb + cSrc;
  const long a32 = (long)32 * lda, b32 = (long)32 * ldb;

  f32x4 acc[4][4] = {};
  f32x4 es[4] = {};
  bf16x8 ones;
#pragma unroll
  for (int j = 0; j < 8; ++j) ones[j] = (short)0x3F80;  // bf16 1.0

  for (int t = 0; t < NT; ++t) {
    // ---- stage tile t into the single buffer
    GLD(pA, tid * 8);                  GLD(pA + a32, 2048 + tid * 8);
    GLD(pA + 2 * a32, 4096 + tid * 8); GLD(pA + 3 * a32, 6144 + tid * 8);
    GLD(pB, 8192 + tid * 8);           GLD(pB + b32, 10240 + tid * 8);
    GLD(pB + 2 * b32, 12288 + tid * 8); GLD(pB + 3 * b32, 14336 + tid * 8);
    VM0;
    BARX;
    // ---- sub-phase 1: bb(8 frags) + a0(4 frags), MFMA mi 0,1
    bf16x8 a0[2][2], a1[2][2], bb[4][2];
#pragma unroll
    for (int ni = 0; ni < 4; ++ni) {
      bb[ni][0] = *(const bf16x8*)&lds[boff + ni * 1024 + x0];
      bb[ni][1] = *(const bf16x8*)&lds[boff + ni * 1024 + x1];
    }
#pragma unroll
    for (int mi = 0; mi < 2; ++mi) {
      a0[mi][0] = *(const bf16x8*)&lds[aoff + mi * 1024 + x0];
      a0[mi][1] = *(const bf16x8*)&lds[aoff + mi * 1024 + x1];
    }
    __builtin_amdgcn_s_setprio(1);
#pragma unroll
    for (int mi = 0; mi < 2; ++mi)
#pragma unroll
      for (int ni = 0; ni < 4; ++ni)
#pragma unroll
        for (int x = 0; x < 2; ++x)
          acc[mi][ni] = __builtin_amdgcn_mfma_f32_16x16x32_bf16(
              a0[mi][x], bb[ni][x], acc[mi][ni], 0, 0, 0);
    if (MODE == 2) {
#pragma unroll
      for (int mi = 0; mi < 2; ++mi)
#pragma unroll
        for (int x = 0; x < 2; ++x)
          es[mi] = __builtin_amdgcn_mfma_f32_16x16x32_bf16(a0[mi][x], ones, es[mi], 0, 0, 0);
    }
    __builtin_amdgcn_s_setprio(0);
    // ---- sub-phase 2: a1(4 frags), MFMA mi 2,3
#pragma unroll
    for (int mi = 0; mi < 2; ++mi) {
      a1[mi][0] = *(const bf16x8*)&lds[aoff + 2048 + mi * 1024 + x0];
      a1[mi][1] = *(const bf16x8*)&lds[aoff + 2048 + mi * 1024 + x1];
    }
    __builtin_amdgcn_s_setprio(1);
#pragma unroll
    for (int mi = 0; mi < 2; ++mi)
#pragma unroll
      for (int ni = 0; ni < 4; ++ni)
#pragma unroll
        for (int x = 0; x < 2; ++x)
          acc[2 + mi][ni] = __builtin_amdgcn_mfma_f32_16x16x32_bf16(
              a1[mi][x], bb[ni][x], acc[2 + mi][ni], 0, 0, 0);
    if (MODE == 2) {
#pragma unroll
      for (int mi = 0; mi < 2; ++mi)
#pragma unroll
        for (int x = 0; x < 2; ++x)
          es[2 + mi] = __builtin_amdgcn_mfma_f32_16x16x32_bf16(a1[mi][x], ones, es[2 + mi], 0, 0, 0);
    }
    __builtin_amdgcn_s_setprio(0);
    BARX;  // all waves done reading -> next tile's stage may overwrite
    pA += 64; pB += 64;
  }

  // ---- epilogue: C/D map col=lane&15, row=4*(lane>>4)+r; acc[mi] = row-block mi*16
  const int r0 = m0 + wm * 64 + lr * 4;
  const int c0 = n0 + wn * 64 + lc;
  if (MODE == 2) {
    float* O = (float*)Cv + (long)bz * sC;
#pragma unroll
    for (int mi = 0; mi < 4; ++mi)
#pragma unroll
      for (int r = 0; r < 4; ++r) {
        const float iv = 1.0f / es[mi][r];  // rowsum of row r0+mi*16+r, lane-local
#pragma unroll
        for (int ni = 0; ni < 4; ++ni)
          O[(long)(r0 + mi * 16 + r) * ldc + (c0 + ni * 16)] = acc[mi][ni][r] * iv;
      }
  } else if (MODE == 0 && n0 >= 2048) {
    // ---- V part: write transposed into VT[b][d][s] (ld 2064), bias pre-added
    unsigned short* VTp = (unsigned short*)vtv + (long)(m0 >> 11) * 1024 * 2064;
    const int sl = (m0 & 2047) + wm * 64 + lr * 4;  // token index within batch
#pragma unroll
    for (int ni = 0; ni < 4; ++ni) {
      const int d = c0 - 2048 + ni * 16;
      const float bv = v_[d];
#pragma unroll
      for (int mi = 0; mi < 4; ++mi)
#pragma unroll
        for (int r = 0; r < 4; ++r)
          VTp[(long)d * 2064 + (sl + mi * 16 + r)] = f2bf(acc[mi][ni][r] + bv);
    }
  } else {
    unsigned short* C = (unsigned short*)Cv + (long)bz * sC;
#pragma unroll
    for (int ni = 0; ni < 4; ++ni) {
      const int col = c0 + ni * 16;
      float bv = 0.0f;
      if (MODE == 0) bv = (col < 1024) ? q_[col] : k_[col - 1024];
#pragma unroll
      for (int mi = 0; mi < 4; ++mi)
#pragma unroll
        for (int r = 0; r < 4; ++r) {
          float val = acc[mi][ni][r];
          val = (MODE == 0) ? (val + bv) : __expf(val * scale);
          C[(long)(r0 + mi * 16 + r) * ldc + col] = f2bf(val);
        }
    }
  }
}

extern "C" void kernel_launch(void* const* d_in, const int* in_sizes, int n_in,
                              void* d_out, int out_size, void* d_ws, size_t ws_size,
                              hipStream_t stream) {
  const float* x  = (const float*)d_in[0];
  const float* Wq = (const float*)d_in[1];
  const float* bq = (const float*)d_in[2];
  const float* Wk = (const float*)d_in[3];
  const float* bk = (const float*)d_in[4];
  const float* Wv = (const float*)d_in[5];
  const float* bv = (const float*)d_in[6];
  float* out = (float*)d_out;

  const int Bb = 4, S = 2048, D = 1024;
  const long MS = (long)Bb * S;  // 8192
  const int LDQ = 2080;          // QK ld (4160 B, breaks 4 KB aliasing)
  const int LDP = 2064;          // E and VT ld

  // ---- workspace layout (liveness-packed) ----
  // [0,16M):   xb (x bf16)          live cvt -> proj
  // [16M,22M): Wt [3072][1024]      live transposes -> proj
  // [33M,66M): QK [8192][2080]      live proj -> scores
  // [66M,83M): VT [4][1024][2064]   live proj -> PV
  // [0,33M):   Sc [4][2048][2064]   live scores -> PV (overlays dead xb+Wt)
  char* ws = (char*)d_ws;
  unsigned short* xb = (unsigned short*)(ws);
  unsigned short* Wt = (unsigned short*)(ws + (16L << 20));
  unsigned short* QK = (unsigned short*)(ws + (33L << 20));
  unsigned short* VT = (unsigned short*)(ws + (66L << 20));
  unsigned short* Sc = (unsigned short*)(ws);

  // 1) x -> bf16
  cvt_f2b<<<2048, 256, 0, stream>>>(x, xb, MS * D / 4);

  // 2) W -> bf16 transposed, concatenated [3072][1024]
  dim3 tb(32, 8);
  dim3 tg(D / 32, D / 32);
  transpose_f2b<<<tg, tb, 0, stream>>>(Wq, Wt, D, D);
  transpose_f2b<<<tg, tb, 0, stream>>>(Wk, Wt + 1024 * 1024, D, D);
  transpose_f2b<<<tg, tb, 0, stream>>>(Wv, Wt + 2 * 1024 * 1024, D, D);

  // 3) fused QKV projection: Q,K row-major -> QK (ld 2080); V -> VT transposed (fused)
  dim3 pgrid(MS / 128, 3072 / 128, 1);
  gemmo<0><<<pgrid, 256, 0, stream>>>(xb, Wt, QK, VT, bq, bk, bv,
                                      D, D, D, LDQ, 1.0f, 0, 0, 0);

  // 4) E = exp(Q @ K^T / 32), bf16 into Sc (ld 2064)
  dim3 sgrid(S / 128, S / 128, Bb);
  gemmo<1><<<sgrid, 256, 0, stream>>>(QK, QK + 1024, Sc, nullptr, nullptr, nullptr, nullptr,
                                      D, LDQ, LDQ, LDP, 1.0f / 32.0f,
                                      (long)S * LDQ, (long)S * LDQ, (long)S * LDP);

  // 5) out = (E @ V) / rowsum(E), fp32 — MFMA-fused denominator, XCD swizzle (512 blocks)
  gemmo<2><<<512, 256, 0, stream>>>(Sc, VT, out, nullptr, nullptr, nullptr, nullptr,
                                    2048, LDP, LDP, D, 1.0f,
                                    (long)S * LDP, (long)D * LDP, (long)S * D);
}